// Round 1
// baseline (844.380 us; speedup 1.0000x reference)
//
#include <hip/hip_runtime.h>
#include <cstdint>

#define ROW_N 8192
#define TPB   256
#define CAP   512

// Order-preserving float->uint32 transform: unsigned compare == float compare.
// Real perturbed values never map to 0, so 0 is a safe "removed" sentinel.
__device__ __forceinline__ unsigned int fkey(float p) {
  unsigned int b = __float_as_uint(p);
  return (b & 0x80000000u) ? ~b : (b | 0x80000000u);
}

__device__ __forceinline__ uint64_t shfl_xor_u64(uint64_t v, int m) {
  unsigned int lo = (unsigned int)v;
  unsigned int hi = (unsigned int)(v >> 32);
  lo = __shfl_xor(lo, m, 64);
  hi = __shfl_xor(hi, m, 64);
  return ((uint64_t)hi << 32) | lo;
}

__device__ __forceinline__ uint64_t wave_max_u64(uint64_t v) {
#pragma unroll
  for (int s = 32; s >= 1; s >>= 1) {
    uint64_t o = shfl_xor_u64(v, s);
    v = (o > v) ? o : v;
  }
  return v;
}

__global__ __launch_bounds__(TPB) void gumbel_topk_kernel(
    const float* __restrict__ logits, const float* __restrict__ u,
    float* __restrict__ out) {
  const int row  = blockIdx.x;
  const int tid  = threadIdx.x;
  const int lane = tid & 63;
  const int wave = tid >> 6;

  __shared__ unsigned int s_cnt;
  __shared__ unsigned int s_twave[4];
  __shared__ uint64_t     s_cand[CAP];

  if (tid == 0) s_cnt = 0;

  const float4* L4 = reinterpret_cast<const float4*>(logits) + (size_t)row * (ROW_N / 4);
  const float4* U4 = reinterpret_cast<const float4*>(u)      + (size_t)row * (ROW_N / 4);
  float4*       O4 = reinterpret_cast<float4*>(out)          + (size_t)row * (ROW_N / 4);

  // ---- Phase A: load, gumbel-perturb, build sortable keys (32/thread in VGPRs)
  unsigned int k[32];
#pragma unroll
  for (int j = 0; j < 8; ++j) {
    int v = j * TPB + tid;
    float4 lv = L4[v];
    float4 uv = U4[v];
    float p;
    p = lv.x - logf(-logf(uv.x + 1e-8f) + 1e-8f); k[j * 4 + 0] = fkey(p);
    p = lv.y - logf(-logf(uv.y + 1e-8f) + 1e-8f); k[j * 4 + 1] = fkey(p);
    p = lv.z - logf(-logf(uv.z + 1e-8f) + 1e-8f); k[j * 4 + 2] = fkey(p);
    p = lv.w - logf(-logf(uv.w + 1e-8f) + 1e-8f); k[j * 4 + 3] = fkey(p);
  }

  // ---- Zero-fill output row early (overlaps the selection compute below).
  {
    float4 z = make_float4(0.f, 0.f, 0.f, 0.f);
#pragma unroll
    for (int j = 0; j < 8; ++j) O4[j * TPB + tid] = z;
  }

  // ---- Phase B: cheap row threshold t <= true 32nd-largest key.
  // t_w = 8th largest of this wave's 64 lane-maxes; t = min over 4 waves.
  unsigned int M = 0;
#pragma unroll
  for (int i = 0; i < 32; ++i) M = max(M, k[i]);

  unsigned int Mx = M, t_w = 0;
#pragma unroll
  for (int it = 0; it < 8; ++it) {
    unsigned int wm = Mx;
#pragma unroll
    for (int s = 32; s >= 1; s >>= 1) {
      unsigned int o = __shfl_xor(wm, s, 64);
      wm = max(wm, o);
    }
    unsigned long long b = __ballot(Mx == wm);
    int leader = (int)__ffsll(b) - 1;
    if (lane == leader) Mx = 0;   // remove one winner element's lane-max
    t_w = wm;                     // after loop: 8th extracted value
  }
  if (lane == 0) s_twave[wave] = t_w;
  __syncthreads();
  unsigned int t = min(min(s_twave[0], s_twave[1]), min(s_twave[2], s_twave[3]));

  // ---- Phase C: collect candidates (all elements with key >= t) as composites.
  // Composite (key<<13)|(8191-idx): bigger = better; ties -> smaller index wins,
  // matching jax.lax.top_k tie-breaking. All composites are distinct.
#pragma unroll
  for (int j = 0; j < 8; ++j) {
#pragma unroll
    for (int c = 0; c < 4; ++c) {
      unsigned int key = k[j * 4 + c];
      if (key >= t) {
        unsigned int slot = atomicAdd(&s_cnt, 1u);
        unsigned int idx  = (unsigned int)(j * TPB + tid) * 4u + (unsigned int)c;
        if (slot < CAP)
          s_cand[slot] = ((uint64_t)key << 13) | (uint64_t)(8191u - idx);
      }
    }
  }
  __syncthreads();
  unsigned int C = s_cnt;

  // ---- Fallback (essentially never taken for iid data): exact per-wave top-32
  // by composite order -> union of 128 provably contains the global top-32.
  if (C > CAP) {
#pragma unroll 1
    for (int it = 0; it < 32; ++it) {
      uint64_t lm = 0;
#pragma unroll
      for (int i = 0; i < 32; ++i) {
        unsigned int idx = (unsigned int)((i >> 2) * TPB + tid) * 4u + (unsigned int)(i & 3);
        uint64_t comp = ((uint64_t)k[i] << 13) | (uint64_t)(8191u - idx);
        if (k[i] != 0u && comp > lm) lm = comp;
      }
      uint64_t wm = wave_max_u64(lm);
      if (lm == wm) {  // unique winner lane (composites distinct)
#pragma unroll
        for (int i = 0; i < 32; ++i) {
          unsigned int idx = (unsigned int)((i >> 2) * TPB + tid) * 4u + (unsigned int)(i & 3);
          uint64_t comp = ((uint64_t)k[i] << 13) | (uint64_t)(8191u - idx);
          if (comp == wm) k[i] = 0u;
        }
      }
      if (lane == 0) s_cand[wave * 32 + it] = wm;
    }
    __syncthreads();
    C = 128;
  }

  // ---- Phase D: wave 0 extracts the exact top-32 composites, then softmax
  // over the ORIGINAL logits at the selected indices.
  float wv = 0.f;
  int   sidx = 0;
  if (wave == 0) {
    int jc = ((int)C + 63) >> 6;   // <= 8
    uint64_t r[8];
#pragma unroll
    for (int j = 0; j < 8; ++j) {
      int vi = lane + (j << 6);
      r[j] = (j < jc && vi < (int)C) ? s_cand[vi] : 0;
    }
    uint64_t mine = 0;
#pragma unroll 1
    for (int it = 0; it < 32; ++it) {
      uint64_t lm = 0;
#pragma unroll
      for (int j = 0; j < 8; ++j)
        if (j < jc && r[j] > lm) lm = r[j];
      uint64_t wm = wave_max_u64(lm);
#pragma unroll
      for (int j = 0; j < 8; ++j)
        if (j < jc && r[j] == wm) r[j] = 0;
      if (lane == it) mine = wm;   // lane i ends holding rank-i composite
    }
    sidx = 8191 - (int)(mine & 8191u);

    float lg = (lane < 32) ? logits[(size_t)row * ROW_N + sidx] : -1e30f;
    float m = lg;
#pragma unroll
    for (int s = 32; s >= 1; s >>= 1) {
      float o = __shfl_xor(m, s, 64);
      m = fmaxf(m, o);
    }
    float e = (lane < 32) ? expf(lg - m) : 0.f;
    float sum = e;
#pragma unroll
    for (int s = 32; s >= 1; s >>= 1) sum += __shfl_xor(sum, s, 64);
    wv = e / sum;
  }

  // Barrier drains all zero-fill stores (compiler emits s_waitcnt vmcnt(0)
  // before s_barrier), so the scatter below safely overwrites them.
  __syncthreads();
  if (wave == 0 && lane < 32) {
    out[(size_t)row * ROW_N + sidx] = wv;
  }
}

extern "C" void kernel_launch(void* const* d_in, const int* in_sizes, int n_in,
                              void* d_out, int out_size, void* d_ws, size_t ws_size,
                              hipStream_t stream) {
  const float* logits = (const float*)d_in[0];
  const float* u      = (const float*)d_in[1];
  float*       out    = (float*)d_out;
  int rows = in_sizes[0] / ROW_N;   // 8192
  gumbel_topk_kernel<<<dim3(rows), dim3(TPB), 0, stream>>>(logits, u, out);
}

// Round 2
// 618.212 us; speedup vs baseline: 1.3658x; 1.3658x over previous
//
#include <hip/hip_runtime.h>
#include <cstdint>

#define ROW_N 8192
#define TPB   256
#define CAP   512

// Order-preserving float->uint32 transform: unsigned compare == float compare.
__device__ __forceinline__ unsigned int fkey(float p) {
  unsigned int b = __float_as_uint(p);
  return (b & 0x80000000u) ? ~b : (b | 0x80000000u);
}
__device__ __forceinline__ float fkey_inv(unsigned int t) {
  unsigned int b = (t & 0x80000000u) ? (t & 0x7fffffffu) : ~t;
  return __uint_as_float(b);
}

// Approximate screening key: key2 = perturbed * log2e, via 2 native v_log_f32.
// w = -ln(u+eps)+eps computed in log2 domain; monotone transform of the precise
// perturbed value. For w < 1e-5 (u extremely close to 1 -> huge gumbel, and the
// region where HW log2's abs error near 1.0 becomes a large *relative* error on
// w) we force candidacy with a saturated key; the precise recompute ranks them.
__device__ __forceinline__ unsigned int akey(float lg, float uu) {
  float l2u = __log2f(uu + 1e-8f);
  float w   = fmaf(l2u, -0.6931471805599453f, 1e-8f);
  float p2  = fmaf(lg, 1.4426950408889634f, -__log2f(w));
  p2 = (w < 1e-5f) ? 3.0e38f : p2;
  return fkey(p2);
}

__device__ __forceinline__ uint64_t shfl_xor_u64(uint64_t v, int m) {
  unsigned int lo = (unsigned int)v, hi = (unsigned int)(v >> 32);
  lo = __shfl_xor(lo, m, 64);
  hi = __shfl_xor(hi, m, 64);
  return ((uint64_t)hi << 32) | lo;
}
__device__ __forceinline__ uint64_t wave_max_u64(uint64_t v) {
#pragma unroll
  for (int s = 32; s >= 1; s >>= 1) {
    uint64_t o = shfl_xor_u64(v, s);
    v = (o > v) ? o : v;
  }
  return v;
}

__global__ __launch_bounds__(TPB) void gumbel_topk_kernel(
    const float* __restrict__ logits, const float* __restrict__ u,
    float* __restrict__ out) {
  const int row  = blockIdx.x;
  const int tid  = threadIdx.x;
  const int lane = tid & 63;
  const int wave = tid >> 6;

  __shared__ unsigned int s_cnt, s_t;
  __shared__ unsigned int s_tmax[TPB];   // per-thread max approx key
  __shared__ unsigned int s_idx[CAP];    // candidate element indices
  __shared__ uint64_t     s_comp[CAP];   // precise composite keys
  __shared__ float        s_lg[CAP];     // candidate original logits
  __shared__ float        s_red[8];      // [0..3] wave maxes, [4..7] wave sums

  if (tid == 0) { s_cnt = 0; s_t = 0xFFFFFFFFu; }

  const float4* L4 = reinterpret_cast<const float4*>(logits) + (size_t)row * (ROW_N / 4);
  const float4* U4 = reinterpret_cast<const float4*>(u)      + (size_t)row * (ROW_N / 4);
  float4*       O4 = reinterpret_cast<float4*>(out)          + (size_t)row * (ROW_N / 4);

  // ---- Phase A: approx screening keys, 32/thread in VGPRs (2 v_log + 3 fma each)
  unsigned int k[32];
  unsigned int M = 0;
#pragma unroll
  for (int j = 0; j < 8; ++j) {
    float4 lv = L4[j * TPB + tid];
    float4 uv = U4[j * TPB + tid];
    k[j * 4 + 0] = akey(lv.x, uv.x);
    k[j * 4 + 1] = akey(lv.y, uv.y);
    k[j * 4 + 2] = akey(lv.z, uv.z);
    k[j * 4 + 3] = akey(lv.w, uv.w);
    M = max(M, max(max(k[j * 4 + 0], k[j * 4 + 1]), max(k[j * 4 + 2], k[j * 4 + 3])));
  }

  // ---- Zero-fill output row early (overlaps everything below; barriers before
  // the final scatter drain vmcnt, ordering these stores first).
  {
    float4 z = make_float4(0.f, 0.f, 0.f, 0.f);
#pragma unroll
    for (int j = 0; j < 8; ++j) O4[j * TPB + tid] = z;
  }

  // ---- Phase B: t = 32nd-largest of the 256 per-thread maxes (<= 32nd-largest
  // element key, since each thread-max IS an element). Rank by LDS counting:
  // broadcast reads, no dependent shuffle chains.
  s_tmax[tid] = M;
  __syncthreads();
  {
    unsigned int cnt = 0;
    const uint4* tm4 = reinterpret_cast<const uint4*>(s_tmax);
#pragma unroll 4
    for (int i = 0; i < TPB / 4; ++i) {
      uint4 v = tm4[i];
      cnt += (v.x > M) + (v.y > M) + (v.z > M) + (v.w > M);
    }
    if (cnt < 32) atomicMin(&s_t, M);  // min over top-32 thread-maxes = 32nd largest
  }
  __syncthreads();
  // Screening threshold with margin Delta = 0.25 log2-units (>= 2x approx error).
  const unsigned int tm = fkey(fkey_inv(s_t) - 0.25f);

  // ---- Phase C: collect candidate indices (approx key >= tm).
#pragma unroll
  for (int j = 0; j < 8; ++j) {
#pragma unroll
    for (int c = 0; c < 4; ++c) {
      if (k[j * 4 + c] >= tm) {
        unsigned int slot = atomicAdd(&s_cnt, 1u);
        if (slot < CAP)
          s_idx[slot] = (unsigned int)(j * TPB + tid) * 4u + (unsigned int)c;
      }
    }
  }
  __syncthreads();
  unsigned int C = s_cnt;

  // ---- Fallback (adversarial ties only; never taken for iid data): exact
  // per-wave top-32 by approx composite -> union of 128 indices.
  if (C > CAP) {
#pragma unroll 1
    for (int it = 0; it < 32; ++it) {
      uint64_t lm = 0;
#pragma unroll
      for (int i = 0; i < 32; ++i) {
        unsigned int idx = (unsigned int)((i >> 2) * TPB + tid) * 4u + (unsigned int)(i & 3);
        uint64_t comp = ((uint64_t)k[i] << 13) | (uint64_t)(8191u - idx);
        if (k[i] != 0u && comp > lm) lm = comp;
      }
      uint64_t wm = wave_max_u64(lm);
      if (lm == wm) {
#pragma unroll
        for (int i = 0; i < 32; ++i) {
          unsigned int idx = (unsigned int)((i >> 2) * TPB + tid) * 4u + (unsigned int)(i & 3);
          uint64_t comp = ((uint64_t)k[i] << 13) | (uint64_t)(8191u - idx);
          if (comp == wm) k[i] = 0u;
        }
      }
      if (lane == 0) s_idx[wave * 32 + it] = 8191u - (unsigned int)(wm & 8191u);
    }
    __syncthreads();
    C = 128;
  }

  // ---- Phase D1: precise recompute for candidates only (~60/row). Rolled loop:
  // ONE textual copy of the precise ocml logf pair. Composite (key<<13)|(8191-idx)
  // is distinct per element; bigger = better, ties -> smaller index (top_k rule).
  const float* Lrow = logits + (size_t)row * ROW_N;
  const float* Urow = u      + (size_t)row * ROW_N;
#pragma unroll 1
  for (unsigned int vi = tid; vi < C; vi += TPB) {
    unsigned int idx = s_idx[vi];
    float lg = Lrow[idx];
    float uu = Urow[idx];
    float p  = lg - logf(-logf(uu + 1e-8f) + 1e-8f);
    s_comp[vi] = ((uint64_t)fkey(p) << 13) | (uint64_t)(8191u - idx);
    s_lg[vi]   = lg;
  }
  __syncthreads();

  // ---- Phase D2: exact selection by rank-counting (rank < 32 <=> selected;
  // composites distinct => exactly 32 selected). Broadcast LDS reads.
  float m_local = -3.4e38f;
  unsigned int sel = 0;
  float lgs[2];
  unsigned int ids[2];
#pragma unroll
  for (int s = 0; s < 2; ++s) {
    unsigned int vi = tid + s * TPB;
    lgs[s] = 0.f; ids[s] = 0;
    if (vi < C) {
      uint64_t mine = s_comp[vi];
      unsigned int cnt = 0;
#pragma unroll 1
      for (unsigned int i = 0; i < C; ++i) cnt += (s_comp[i] > mine) ? 1u : 0u;
      if (cnt < 32) {
        sel |= (1u << s);
        lgs[s] = s_lg[vi];
        ids[s] = s_idx[vi];
        m_local = fmaxf(m_local, lgs[s]);
      }
    }
  }

  // Block-wide max of selected logits.
  float m = m_local;
#pragma unroll
  for (int s = 32; s >= 1; s >>= 1) m = fmaxf(m, __shfl_xor(m, s, 64));
  if (lane == 0) s_red[wave] = m;
  __syncthreads();
  m = fmaxf(fmaxf(s_red[0], s_red[1]), fmaxf(s_red[2], s_red[3]));

  float e0 = (sel & 1u) ? expf(lgs[0] - m) : 0.f;
  float e1 = (sel & 2u) ? expf(lgs[1] - m) : 0.f;
  float sum = e0 + e1;
#pragma unroll
  for (int s = 32; s >= 1; s >>= 1) sum += __shfl_xor(sum, s, 64);
  if (lane == 0) s_red[4 + wave] = sum;
  __syncthreads();
  sum = (s_red[4] + s_red[5]) + (s_red[6] + s_red[7]);

  // Scatter the 32 softmax weights (ordered after the zero-fill by the barriers).
  float* Orow = out + (size_t)row * ROW_N;
  if (sel & 1u) Orow[ids[0]] = e0 / sum;
  if (sel & 2u) Orow[ids[1]] = e1 / sum;
}

extern "C" void kernel_launch(void* const* d_in, const int* in_sizes, int n_in,
                              void* d_out, int out_size, void* d_ws, size_t ws_size,
                              hipStream_t stream) {
  const float* logits = (const float*)d_in[0];
  const float* u      = (const float*)d_in[1];
  float*       out    = (float*)d_out;
  int rows = in_sizes[0] / ROW_N;   // 8192
  gumbel_topk_kernel<<<dim3(rows), dim3(TPB), 0, stream>>>(logits, u, out);
}